// Round 6
// baseline (313.492 us; speedup 1.0000x reference)
//
#include <hip/hip_runtime.h>
#include <math.h>
#include <stdint.h>

// Problem constants (from the reference):
//   B=262144 items, W=8 context window, K=3 negatives, V=100000 vocab, E=128 dim
#define B_ITEMS 262144
#define W_CTX   8
#define K_NEG   3
#define E_DIM   128
#define V_VOCAB 100000
#define NSLICE  8
#define SLICE_E 16   // elems per slice (fp8 -> 16 B per row-slice)

typedef _Float16 half_t;
typedef __attribute__((ext_vector_type(2))) _Float16 half2_t;
typedef __attribute__((ext_vector_type(2))) float   fvec2;
typedef __attribute__((ext_vector_type(4))) int     intv4;

#define TBL_BYTES ((size_t)V_VOCAB * E_DIM)              // 12.8 MB per fp8 table
#define PP_BYTES  ((size_t)NSLICE * B_ITEMS * 4)         // 8.4 MB packed f16x2 partials
#define WS_NEED   (2 * TBL_BYTES + PP_BYTES)             // 34.0 MB

#if __has_builtin(__builtin_amdgcn_cvt_pk_f32_fp8) && __has_builtin(__builtin_amdgcn_cvt_pk_fp8_f32)
#define HAVE_FP8 1
#else
#define HAVE_FP8 0
#endif

// Numerically stable log-sigmoid: log_sigmoid(x) = min(x,0) - log1p(exp(-|x|))
__device__ __forceinline__ float log_sigmoid_f(float x) {
    return fminf(x, 0.0f) - log1pf(expf(-fabsf(x)));
}

__global__ void init_out_kernel(float* out) {
    if (threadIdx.x == 0 && blockIdx.x == 0) out[0] = 0.0f;
}

#if HAVE_FP8
// NOTE: the builtin's word-select arg must be a compile-time constant -> template.
template <bool HI>
__device__ __forceinline__ fvec2 cvt2(uint32_t u) {
    return __builtin_amdgcn_cvt_pk_f32_fp8((int)u, HI);
}

__device__ __forceinline__ uint4 enc16fp8(float4 a, float4 b, float4 c, float4 d) {
    int w0 = __builtin_amdgcn_cvt_pk_fp8_f32(a.x, a.y, 0, false);
    w0     = __builtin_amdgcn_cvt_pk_fp8_f32(a.z, a.w, w0, true);
    int w1 = __builtin_amdgcn_cvt_pk_fp8_f32(b.x, b.y, 0, false);
    w1     = __builtin_amdgcn_cvt_pk_fp8_f32(b.z, b.w, w1, true);
    int w2 = __builtin_amdgcn_cvt_pk_fp8_f32(c.x, c.y, 0, false);
    w2     = __builtin_amdgcn_cvt_pk_fp8_f32(c.z, c.w, w2, true);
    int w3 = __builtin_amdgcn_cvt_pk_fp8_f32(d.x, d.y, 0, false);
    w3     = __builtin_amdgcn_cvt_pk_fp8_f32(d.z, d.w, w3, true);
    return make_uint4((uint32_t)w0, (uint32_t)w1, (uint32_t)w2, (uint32_t)w3);
}

// Both tables f32 -> fp8 e4m3, SLICE-MAJOR layout: dst[s][v][16B].
// Thread gid -> (v = gid>>3, s = gid&7). Also zeroes out[0].
__global__ void __launch_bounds__(256) convert_slice_fp8(
    const float* __restrict__ ctx, const float* __restrict__ tgt,
    uint4* __restrict__ ctx8, uint4* __restrict__ tgt8, float* __restrict__ out)
{
    const int gid = blockIdx.x * 256 + threadIdx.x;
    if (gid == 0) out[0] = 0.0f;
    if (gid >= V_VOCAB * NSLICE) return;
    const int v = gid >> 3, s = gid & 7;

    const float4* c4 = reinterpret_cast<const float4*>(ctx + (size_t)v * E_DIM + s * SLICE_E);
    const float4* t4 = reinterpret_cast<const float4*>(tgt + (size_t)v * E_DIM + s * SLICE_E);
    const uint32_t oidx = (uint32_t)s * V_VOCAB + v;   // slice-major row-slice index
    ctx8[oidx] = enc16fp8(c4[0], c4[1], c4[2], c4[3]);
    tgt8[oidx] = enc16fp8(t4[0], t4[1], t4[2], t4[3]);
}

// Pass B: slice = blockIdx & 7 (matches XCD on MI355X round-robin dispatch).
// One lane = one item. 12 gathers of 16 B from the XCD-resident slice tables.
// Writes packed f16x2 (pos_partial, neg_partial) per (slice, item).
__global__ void __launch_bounds__(256, 8) cbow_slice_kernel(
    const int*  __restrict__ targets,     // [B]
    const int*  __restrict__ contexts,    // [B, W]
    const int*  __restrict__ negsamples,  // [B, K]
    const char* __restrict__ ctx8,        // [8][V][16] fp8, slice-major
    const char* __restrict__ tgt8,        // [8][V][16] fp8, slice-major
    uint32_t*   __restrict__ PP)          // [8][B] packed f16x2
{
    const int s = blockIdx.x & 7;
    const int b = (blockIdx.x >> 3) * 256 + threadIdx.x;   // exact: 1024*256 = B

    // ---- indices: non-temporal (streaming; don't evict resident slices) ----
    const intv4 c0 = __builtin_nontemporal_load(
        reinterpret_cast<const intv4*>(contexts + (size_t)b * W_CTX));
    const intv4 c1 = __builtin_nontemporal_load(
        reinterpret_cast<const intv4*>(contexts + (size_t)b * W_CTX + 4));
    const int n0 = __builtin_nontemporal_load(negsamples + (size_t)b * K_NEG + 0);
    const int n1 = __builtin_nontemporal_load(negsamples + (size_t)b * K_NEG + 1);
    const int n2 = __builtin_nontemporal_load(negsamples + (size_t)b * K_NEG + 2);
    const int t  = __builtin_nontemporal_load(targets + b);

    const char* cb = ctx8 + (size_t)s * V_VOCAB * 16;
    const char* tb = tgt8 + (size_t)s * V_VOCAB * 16;

    // ---- target row-slice: 16 fp8 -> 8 fvec2 ----
    const uint4 tv = *reinterpret_cast<const uint4*>(tb + ((uint32_t)t << 4));
    fvec2 tg2[8];
    tg2[0] = cvt2<false>(tv.x); tg2[1] = cvt2<true>(tv.x);
    tg2[2] = cvt2<false>(tv.y); tg2[3] = cvt2<true>(tv.y);
    tg2[4] = cvt2<false>(tv.z); tg2[5] = cvt2<true>(tv.z);
    tg2[6] = cvt2<false>(tv.w); tg2[7] = cvt2<true>(tv.w);

    fvec2 pa = {0.f, 0.f}, pb = {0.f, 0.f};   // pos: two chains
    fvec2 qa = {0.f, 0.f}, qb = {0.f, 0.f};   // neg: two chains

    auto row = [&](int idx, fvec2& x, fvec2& y) {
        const uint4 rv = *reinterpret_cast<const uint4*>(cb + ((uint32_t)idx << 4));
        x += cvt2<false>(rv.x) * tg2[0];
        x += cvt2<true >(rv.x) * tg2[1];
        x += cvt2<false>(rv.y) * tg2[2];
        x += cvt2<true >(rv.y) * tg2[3];
        y += cvt2<false>(rv.z) * tg2[4];
        y += cvt2<true >(rv.z) * tg2[5];
        y += cvt2<false>(rv.w) * tg2[6];
        y += cvt2<true >(rv.w) * tg2[7];
    };

    row(c0.x, pa, pb); row(c0.y, pa, pb); row(c0.z, pa, pb); row(c0.w, pa, pb);
    row(c1.x, pa, pb); row(c1.y, pa, pb); row(c1.z, pa, pb); row(c1.w, pa, pb);
    row(n0,   qa, qb); row(n1,   qa, qb); row(n2,   qa, qb);

    const float pos = (pa.x + pa.y) + (pb.x + pb.y);
    const float neg = (qa.x + qa.y) + (qb.x + qb.y);

    const half2_t ph = {(half_t)pos, (half_t)neg};
    __builtin_nontemporal_store(__builtin_bit_cast(uint32_t, ph),
                                PP + (size_t)s * B_ITEMS + b);
}

// Pass C: per item sum the 8 slice-partials, logsig, reduce to the scalar loss.
__global__ void __launch_bounds__(256) cbow_reduce_kernel(
    const uint32_t* __restrict__ PP, float* __restrict__ out)
{
    const int b    = blockIdx.x * 256 + threadIdx.x;
    const int lane = threadIdx.x & 63;
    const int wib  = threadIdx.x >> 6;

    float pos = 0.f, neg = 0.f;
    #pragma unroll
    for (int s = 0; s < NSLICE; ++s) {
        const uint32_t u = __builtin_nontemporal_load(PP + (size_t)s * B_ITEMS + b);
        const half2_t h = __builtin_bit_cast(half2_t, u);
        pos += (float)h[0];
        neg += (float)h[1];
    }
    float per = log_sigmoid_f(pos * (1.0f / W_CTX)) + log_sigmoid_f(-neg);

    #pragma unroll
    for (int off = 32; off > 0; off >>= 1)
        per += __shfl_xor(per, off, 64);

    __shared__ float sm[4];
    if (lane == 0) sm[wib] = per;
    __syncthreads();
    if (threadIdx.x == 0)
        atomicAdd(out, (sm[0] + sm[1] + sm[2] + sm[3]) * (-1.0f / (float)B_ITEMS));
}
#endif  // HAVE_FP8

// Safe fallback: f32 gathers, 16 lanes/item (no workspace needed).
__global__ void __launch_bounds__(256, 8) cbow_f32_kernel(
    const int* __restrict__ targets, const int* __restrict__ contexts,
    const int* __restrict__ negsamples, const float* __restrict__ target_W,
    const float* __restrict__ context_W, float* __restrict__ out)
{
    const int lane = threadIdx.x & 63;
    const int wib  = threadIdx.x >> 6;
    const int wid  = blockIdx.x * (blockDim.x >> 6) + wib;
    const int grp  = lane >> 4;
    const int sub  = lane & 15;

    float wave_sum = 0.0f;
    #pragma unroll
    for (int i = 0; i < 4; ++i) {
        const int b = wid * 16 + i * 4 + grp;
        const int4 c0 = *reinterpret_cast<const int4*>(&contexts[b * W_CTX]);
        const int4 c1 = *reinterpret_cast<const int4*>(&contexts[b * W_CTX + 4]);
        const int  n0 = negsamples[b * K_NEG + 0];
        const int  n1 = negsamples[b * K_NEG + 1];
        const int  n2 = negsamples[b * K_NEG + 2];
        const int  t  = targets[b];
        float tf[8];
        {
            const float4 f0 = *reinterpret_cast<const float4*>(&target_W[(size_t)t * E_DIM + sub * 8]);
            const float4 f1 = *reinterpret_cast<const float4*>(&target_W[(size_t)t * E_DIM + sub * 8 + 4]);
            tf[0]=f0.x; tf[1]=f0.y; tf[2]=f0.z; tf[3]=f0.w;
            tf[4]=f1.x; tf[5]=f1.y; tf[6]=f1.z; tf[7]=f1.w;
        }
        float p = 0.f, q = 0.f;
        auto row = [&](int idx, float& a) {
            const float4 f0 = *reinterpret_cast<const float4*>(&context_W[(size_t)idx * E_DIM + sub * 8]);
            const float4 f1 = *reinterpret_cast<const float4*>(&context_W[(size_t)idx * E_DIM + sub * 8 + 4]);
            a += f0.x*tf[0] + f0.y*tf[1] + f0.z*tf[2] + f0.w*tf[3]
               + f1.x*tf[4] + f1.y*tf[5] + f1.z*tf[6] + f1.w*tf[7];
        };
        row(c0.x,p); row(c0.y,p); row(c0.z,p); row(c0.w,p);
        row(c1.x,p); row(c1.y,p); row(c1.z,p); row(c1.w,p);
        row(n0,q); row(n1,q); row(n2,q);
        #pragma unroll
        for (int off = 8; off > 0; off >>= 1) {
            p += __shfl_xor(p, off, 64);
            q += __shfl_xor(q, off, 64);
        }
        wave_sum += log_sigmoid_f(p * (1.0f / W_CTX)) + log_sigmoid_f(-q);
    }
    wave_sum += __shfl_xor(wave_sum, 16, 64);
    wave_sum += __shfl_xor(wave_sum, 32, 64);
    __shared__ float sm[4];
    if (lane == 0) sm[wib] = wave_sum;
    __syncthreads();
    if (threadIdx.x == 0)
        atomicAdd(out, (sm[0]+sm[1]+sm[2]+sm[3]) * (-1.0f / (float)B_ITEMS));
}

extern "C" void kernel_launch(void* const* d_in, const int* in_sizes, int n_in,
                              void* d_out, int out_size, void* d_ws, size_t ws_size,
                              hipStream_t stream) {
    const int*   targets    = (const int*)  d_in[0];
    const int*   contexts   = (const int*)  d_in[1];
    const int*   negsamples = (const int*)  d_in[2];
    const float* target_W   = (const float*)d_in[3];
    const float* context_W  = (const float*)d_in[4];
    float*       out        = (float*)      d_out;

#if HAVE_FP8
    if (ws_size >= WS_NEED) {
        char* ctx8 = (char*)d_ws;
        char* tgt8 = (char*)d_ws + TBL_BYTES;
        uint32_t* PP = (uint32_t*)((char*)d_ws + 2 * TBL_BYTES);

        // A: convert both tables to slice-major fp8 (also zeroes out[0]).
        convert_slice_fp8<<<(V_VOCAB * NSLICE + 255) / 256, 256, 0, stream>>>(
            context_W, target_W, (uint4*)ctx8, (uint4*)tgt8, out);
        // B: 8192 blocks; slice = bid&7 -> XCD-resident gather slices.
        cbow_slice_kernel<<<(B_ITEMS / 256) * NSLICE, 256, 0, stream>>>(
            targets, contexts, negsamples, ctx8, tgt8, PP);
        // C: reduce partials -> scalar loss.
        cbow_reduce_kernel<<<B_ITEMS / 256, 256, 0, stream>>>(PP, out);
        return;
    }
#endif
    init_out_kernel<<<1, 64, 0, stream>>>(out);
    cbow_f32_kernel<<<4096, 256, 0, stream>>>(
        targets, contexts, negsamples, target_W, context_W, out);
}

// Round 7
// 277.028 us; speedup vs baseline: 1.1316x; 1.1316x over previous
//
#include <hip/hip_runtime.h>
#include <math.h>
#include <stdint.h>

// Problem constants (from the reference):
//   B=262144 items, W=8 context window, K=3 negatives, V=100000 vocab, E=128 dim
#define B_ITEMS 262144
#define W_CTX   8
#define K_NEG   3
#define E_DIM   128
#define V_VOCAB 100000
#define NSLICE  8
#define SLICE_E 16   // elems per slice (fp8 -> 16 B per row-slice)

typedef _Float16 half_t;
typedef __attribute__((ext_vector_type(2))) _Float16 half2_t;
typedef __attribute__((ext_vector_type(2))) float   fvec2;
typedef __attribute__((ext_vector_type(4))) int     intv4;

#define TBL_BYTES ((size_t)V_VOCAB * E_DIM)              // 12.8 MB per fp8 table
#define PP_BYTES  ((size_t)NSLICE * B_ITEMS * 4)         // 8.4 MB packed f16x2 partials
#define WS_NEED   (2 * TBL_BYTES + PP_BYTES)             // 34.0 MB

// NOTE (R6 lesson): do NOT gate on __has_builtin(__builtin_amdgcn_*) — it
// evaluates to 0 in the HOST pass, silently compiling out the launch branch.
// The fp8 cvt builtins are available on gfx950 (device-compile proven R5/R6).

// Numerically stable log-sigmoid: log_sigmoid(x) = min(x,0) - log1p(exp(-|x|))
__device__ __forceinline__ float log_sigmoid_f(float x) {
    return fminf(x, 0.0f) - log1pf(expf(-fabsf(x)));
}

__global__ void init_out_kernel(float* out) {
    if (threadIdx.x == 0 && blockIdx.x == 0) out[0] = 0.0f;
}

// Word-select arg must be a compile-time constant -> template.
template <bool HI>
__device__ __forceinline__ fvec2 cvt2(uint32_t u) {
    return __builtin_amdgcn_cvt_pk_f32_fp8((int)u, HI);
}

__device__ __forceinline__ uint4 enc16fp8(float4 a, float4 b, float4 c, float4 d) {
    int w0 = __builtin_amdgcn_cvt_pk_fp8_f32(a.x, a.y, 0, false);
    w0     = __builtin_amdgcn_cvt_pk_fp8_f32(a.z, a.w, w0, true);
    int w1 = __builtin_amdgcn_cvt_pk_fp8_f32(b.x, b.y, 0, false);
    w1     = __builtin_amdgcn_cvt_pk_fp8_f32(b.z, b.w, w1, true);
    int w2 = __builtin_amdgcn_cvt_pk_fp8_f32(c.x, c.y, 0, false);
    w2     = __builtin_amdgcn_cvt_pk_fp8_f32(c.z, c.w, w2, true);
    int w3 = __builtin_amdgcn_cvt_pk_fp8_f32(d.x, d.y, 0, false);
    w3     = __builtin_amdgcn_cvt_pk_fp8_f32(d.z, d.w, w3, true);
    return make_uint4((uint32_t)w0, (uint32_t)w1, (uint32_t)w2, (uint32_t)w3);
}

// Both tables f32 -> fp8 e4m3, SLICE-MAJOR layout: dst[s][v][16B].
// Thread gid -> (v = gid>>3, s = gid&7). Also zeroes out[0].
__global__ void __launch_bounds__(256) convert_slice_fp8(
    const float* __restrict__ ctx, const float* __restrict__ tgt,
    uint4* __restrict__ ctx8, uint4* __restrict__ tgt8, float* __restrict__ out)
{
    const int gid = blockIdx.x * 256 + threadIdx.x;
    if (gid == 0) out[0] = 0.0f;
    if (gid >= V_VOCAB * NSLICE) return;
    const int v = gid >> 3, s = gid & 7;

    const float4* c4 = reinterpret_cast<const float4*>(ctx + (size_t)v * E_DIM + s * SLICE_E);
    const float4* t4 = reinterpret_cast<const float4*>(tgt + (size_t)v * E_DIM + s * SLICE_E);
    const uint32_t oidx = (uint32_t)s * V_VOCAB + v;   // slice-major row-slice index
    ctx8[oidx] = enc16fp8(c4[0], c4[1], c4[2], c4[3]);
    tgt8[oidx] = enc16fp8(t4[0], t4[1], t4[2], t4[3]);
}

// Pass B: slice = blockIdx & 7 (matches XCD round-robin dispatch on MI355X).
// One lane = one item. 12 gathers of 16 B from the XCD-resident slice tables.
// Writes packed f16x2 (pos_partial, neg_partial) per (slice, item).
// Correctness is mapping-independent; only locality depends on it.
__global__ void __launch_bounds__(256, 8) cbow_slice_kernel(
    const int*  __restrict__ targets,     // [B]
    const int*  __restrict__ contexts,    // [B, W]
    const int*  __restrict__ negsamples,  // [B, K]
    const char* __restrict__ ctx8,        // [8][V][16] fp8, slice-major
    const char* __restrict__ tgt8,        // [8][V][16] fp8, slice-major
    uint32_t*   __restrict__ PP)          // [8][B] packed f16x2
{
    const int s = blockIdx.x & 7;
    const int b = (blockIdx.x >> 3) * 256 + threadIdx.x;   // exact: 1024*256 = B

    // ---- indices: non-temporal (streaming; don't evict resident slices) ----
    const intv4 c0 = __builtin_nontemporal_load(
        reinterpret_cast<const intv4*>(contexts + (size_t)b * W_CTX));
    const intv4 c1 = __builtin_nontemporal_load(
        reinterpret_cast<const intv4*>(contexts + (size_t)b * W_CTX + 4));
    const int n0 = __builtin_nontemporal_load(negsamples + (size_t)b * K_NEG + 0);
    const int n1 = __builtin_nontemporal_load(negsamples + (size_t)b * K_NEG + 1);
    const int n2 = __builtin_nontemporal_load(negsamples + (size_t)b * K_NEG + 2);
    const int t  = __builtin_nontemporal_load(targets + b);

    const char* cb = ctx8 + (size_t)s * V_VOCAB * 16;
    const char* tb = tgt8 + (size_t)s * V_VOCAB * 16;

    // ---- target row-slice: 16 fp8 -> 8 fvec2 ----
    const uint4 tv = *reinterpret_cast<const uint4*>(tb + ((uint32_t)t << 4));
    fvec2 tg2[8];
    tg2[0] = cvt2<false>(tv.x); tg2[1] = cvt2<true>(tv.x);
    tg2[2] = cvt2<false>(tv.y); tg2[3] = cvt2<true>(tv.y);
    tg2[4] = cvt2<false>(tv.z); tg2[5] = cvt2<true>(tv.z);
    tg2[6] = cvt2<false>(tv.w); tg2[7] = cvt2<true>(tv.w);

    fvec2 pa = {0.f, 0.f}, pb = {0.f, 0.f};   // pos: two chains
    fvec2 qa = {0.f, 0.f}, qb = {0.f, 0.f};   // neg: two chains

    auto row = [&](int idx, fvec2& x, fvec2& y) {
        const uint4 rv = *reinterpret_cast<const uint4*>(cb + ((uint32_t)idx << 4));
        x += cvt2<false>(rv.x) * tg2[0];
        x += cvt2<true >(rv.x) * tg2[1];
        x += cvt2<false>(rv.y) * tg2[2];
        x += cvt2<true >(rv.y) * tg2[3];
        y += cvt2<false>(rv.z) * tg2[4];
        y += cvt2<true >(rv.z) * tg2[5];
        y += cvt2<false>(rv.w) * tg2[6];
        y += cvt2<true >(rv.w) * tg2[7];
    };

    row(c0.x, pa, pb); row(c0.y, pa, pb); row(c0.z, pa, pb); row(c0.w, pa, pb);
    row(c1.x, pa, pb); row(c1.y, pa, pb); row(c1.z, pa, pb); row(c1.w, pa, pb);
    row(n0,   qa, qb); row(n1,   qa, qb); row(n2,   qa, qb);

    const float pos = (pa.x + pa.y) + (pb.x + pb.y);
    const float neg = (qa.x + qa.y) + (qb.x + qb.y);

    const half2_t ph = {(half_t)pos, (half_t)neg};
    __builtin_nontemporal_store(__builtin_bit_cast(uint32_t, ph),
                                PP + (size_t)s * B_ITEMS + b);
}

// Pass C: per item sum the 8 slice-partials, logsig, reduce to the scalar loss.
__global__ void __launch_bounds__(256) cbow_reduce_kernel(
    const uint32_t* __restrict__ PP, float* __restrict__ out)
{
    const int b    = blockIdx.x * 256 + threadIdx.x;
    const int lane = threadIdx.x & 63;
    const int wib  = threadIdx.x >> 6;

    float pos = 0.f, neg = 0.f;
    #pragma unroll
    for (int s = 0; s < NSLICE; ++s) {
        const uint32_t u = __builtin_nontemporal_load(PP + (size_t)s * B_ITEMS + b);
        const half2_t h = __builtin_bit_cast(half2_t, u);
        pos += (float)h[0];
        neg += (float)h[1];
    }
    float per = log_sigmoid_f(pos * (1.0f / W_CTX)) + log_sigmoid_f(-neg);

    #pragma unroll
    for (int off = 32; off > 0; off >>= 1)
        per += __shfl_xor(per, off, 64);

    __shared__ float sm[4];
    if (lane == 0) sm[wib] = per;
    __syncthreads();
    if (threadIdx.x == 0)
        atomicAdd(out, (sm[0] + sm[1] + sm[2] + sm[3]) * (-1.0f / (float)B_ITEMS));
}

// Safe fallback: f32 gathers, 16 lanes/item (no workspace needed).
__global__ void __launch_bounds__(256, 8) cbow_f32_kernel(
    const int* __restrict__ targets, const int* __restrict__ contexts,
    const int* __restrict__ negsamples, const float* __restrict__ target_W,
    const float* __restrict__ context_W, float* __restrict__ out)
{
    const int lane = threadIdx.x & 63;
    const int wib  = threadIdx.x >> 6;
    const int wid  = blockIdx.x * (blockDim.x >> 6) + wib;
    const int grp  = lane >> 4;
    const int sub  = lane & 15;

    float wave_sum = 0.0f;
    #pragma unroll
    for (int i = 0; i < 4; ++i) {
        const int b = wid * 16 + i * 4 + grp;
        const int4 c0 = *reinterpret_cast<const int4*>(&contexts[b * W_CTX]);
        const int4 c1 = *reinterpret_cast<const int4*>(&contexts[b * W_CTX + 4]);
        const int  n0 = negsamples[b * K_NEG + 0];
        const int  n1 = negsamples[b * K_NEG + 1];
        const int  n2 = negsamples[b * K_NEG + 2];
        const int  t  = targets[b];
        float tf[8];
        {
            const float4 f0 = *reinterpret_cast<const float4*>(&target_W[(size_t)t * E_DIM + sub * 8]);
            const float4 f1 = *reinterpret_cast<const float4*>(&target_W[(size_t)t * E_DIM + sub * 8 + 4]);
            tf[0]=f0.x; tf[1]=f0.y; tf[2]=f0.z; tf[3]=f0.w;
            tf[4]=f1.x; tf[5]=f1.y; tf[6]=f1.z; tf[7]=f1.w;
        }
        float p = 0.f, q = 0.f;
        auto row = [&](int idx, float& a) {
            const float4 f0 = *reinterpret_cast<const float4*>(&context_W[(size_t)idx * E_DIM + sub * 8]);
            const float4 f1 = *reinterpret_cast<const float4*>(&context_W[(size_t)idx * E_DIM + sub * 8 + 4]);
            a += f0.x*tf[0] + f0.y*tf[1] + f0.z*tf[2] + f0.w*tf[3]
               + f1.x*tf[4] + f1.y*tf[5] + f1.z*tf[6] + f1.w*tf[7];
        };
        row(c0.x,p); row(c0.y,p); row(c0.z,p); row(c0.w,p);
        row(c1.x,p); row(c1.y,p); row(c1.z,p); row(c1.w,p);
        row(n0,q); row(n1,q); row(n2,q);
        #pragma unroll
        for (int off = 8; off > 0; off >>= 1) {
            p += __shfl_xor(p, off, 64);
            q += __shfl_xor(q, off, 64);
        }
        wave_sum += log_sigmoid_f(p * (1.0f / W_CTX)) + log_sigmoid_f(-q);
    }
    wave_sum += __shfl_xor(wave_sum, 16, 64);
    wave_sum += __shfl_xor(wave_sum, 32, 64);
    __shared__ float sm[4];
    if (lane == 0) sm[wib] = wave_sum;
    __syncthreads();
    if (threadIdx.x == 0)
        atomicAdd(out, (sm[0]+sm[1]+sm[2]+sm[3]) * (-1.0f / (float)B_ITEMS));
}

extern "C" void kernel_launch(void* const* d_in, const int* in_sizes, int n_in,
                              void* d_out, int out_size, void* d_ws, size_t ws_size,
                              hipStream_t stream) {
    const int*   targets    = (const int*)  d_in[0];
    const int*   contexts   = (const int*)  d_in[1];
    const int*   negsamples = (const int*)  d_in[2];
    const float* target_W   = (const float*)d_in[3];
    const float* context_W  = (const float*)d_in[4];
    float*       out        = (float*)      d_out;

    if (ws_size >= WS_NEED) {
        char* ctx8 = (char*)d_ws;
        char* tgt8 = (char*)d_ws + TBL_BYTES;
        uint32_t* PP = (uint32_t*)((char*)d_ws + 2 * TBL_BYTES);

        // A: convert both tables to slice-major fp8 (also zeroes out[0]).
        convert_slice_fp8<<<(V_VOCAB * NSLICE + 255) / 256, 256, 0, stream>>>(
            context_W, target_W, (uint4*)ctx8, (uint4*)tgt8, out);
        // B: 8192 blocks; slice = bid&7 -> XCD-resident gather slices.
        cbow_slice_kernel<<<(B_ITEMS / 256) * NSLICE, 256, 0, stream>>>(
            targets, contexts, negsamples, ctx8, tgt8, PP);
        // C: reduce partials -> scalar loss.
        cbow_reduce_kernel<<<B_ITEMS / 256, 256, 0, stream>>>(PP, out);
        return;
    }

    init_out_kernel<<<1, 64, 0, stream>>>(out);
    cbow_f32_kernel<<<4096, 256, 0, stream>>>(
        targets, contexts, negsamples, target_W, context_W, out);
}